// Round 1
// baseline (1353.843 us; speedup 1.0000x reference)
//
#include <hip/hip_runtime.h>

#define NROWS 16384      // 16*32*32
#define EDIM  256
#define NE    8192
#define OUT_N 4194304    // 16*256*32*32
#define NSPLIT 8
#define NPER  (NE / NSPLIT)  // 1024

// ws layout, offsets in 4-byte units
#define WS_S    0
#define WS_E    (WS_S + NROWS)
#define WS_BD   (WS_E + NE)
#define WS_BJ   (WS_BD + NROWS * NSPLIT)
#define WS_IDX  (WS_BJ + NROWS * NSPLIT)
#define WS_LOSS (WS_IDX + NROWS)

// ---------------- row sums ----------------
// S[r] = sum_c z[b][c][h][w]^2, r = b*1024 + h*32 + w.
// Lanes map to consecutive r -> consecutive hw -> coalesced for each c.
__global__ void k_rowsum_z(const float* __restrict__ z, float* __restrict__ S) {
    int r = blockIdx.x * 256 + threadIdx.x;
    int b = r >> 10, hw = r & 1023;
    const float* p = z + (size_t)b * 262144 + hw;
    double s = 0.0;
#pragma unroll 8
    for (int c = 0; c < 256; ++c) {
        float v = p[(size_t)c * 1024];
        s += (double)v * (double)v;
    }
    S[r] = (float)s;
}

// E[j] = sum_k emb[j][k]^2. One 64-lane wave per row.
__global__ void k_rowsum_e(const float* __restrict__ emb, float* __restrict__ E) {
    int row  = blockIdx.x * 4 + (threadIdx.x >> 6);
    int lane = threadIdx.x & 63;
    const float* p = emb + (size_t)row * 256;
    double s = 0.0;
#pragma unroll
    for (int i = 0; i < 4; ++i) {
        float v = p[lane + i * 64];
        s += (double)v * (double)v;
    }
    for (int off = 32; off; off >>= 1) s += __shfl_down(s, off, 64);
    if (lane == 0) E[row] = (float)s;
}

// ---------------- tiled GEMM + argmin ----------------
// grid (NROWS/64, NSPLIT), block 256. Each block: 64 rows x 1024 codes,
// chunked 64 codes at a time, K accumulated fully (4 x BK=64) before argmin.
__global__ __launch_bounds__(256, 4) void k_gemm_argmin(
    const float* __restrict__ z, const float* __restrict__ emb,
    const float* __restrict__ S, const float* __restrict__ E,
    float* __restrict__ bd_out, int* __restrict__ bj_out) {
    __shared__ float As[64][68];   // [k][m], +4 pad keeps float4 alignment
    __shared__ float Bs[64][68];   // [k][n]

    const int tid = threadIdx.x;
    const int tx = tid & 15;       // row group (4 rows)
    const int ty = tid >> 4;       // col group (4 cols)
    const int row0 = blockIdx.x * 64;
    const int b = row0 >> 10, hw0 = row0 & 1023;   // 64-row tile never crosses b
    const float* zb = z + (size_t)b * 262144 + hw0;

    float Sr[4];
#pragma unroll
    for (int i = 0; i < 4; ++i) Sr[i] = S[row0 + tx * 4 + i];

    float bd[4] = {__builtin_inff(), __builtin_inff(), __builtin_inff(), __builtin_inff()};
    int   bj[4] = {0x7fffffff, 0x7fffffff, 0x7fffffff, 0x7fffffff};

    for (int chunk = 0; chunk < NPER / 64; ++chunk) {
        const int nbase = blockIdx.y * NPER + chunk * 64;
        float acc[4][4];
#pragma unroll
        for (int i = 0; i < 4; ++i)
#pragma unroll
            for (int j = 0; j < 4; ++j) acc[i][j] = 0.0f;

        for (int kt = 0; kt < 4; ++kt) {
            const int kbase = kt * 64;
            // stage A: 64 rows x 64 c. float4 across rows (contiguous hw).
#pragma unroll
            for (int it = 0; it < 4; ++it) {
                int e  = tid + it * 256;       // float4 index 0..1023
                int m4 = (e & 15) * 4;
                int k  = e >> 4;
                float4 v = *(const float4*)(zb + (size_t)(kbase + k) * 1024 + m4);
                *(float4*)&As[k][m4] = v;
            }
            // stage B: 64 codes x 64 k, k-fast scalar (coalesced 256B runs).
#pragma unroll
            for (int it = 0; it < 16; ++it) {
                int e = tid + it * 256;        // 0..4095
                int k = e & 63;
                int n = e >> 6;
                Bs[k][n] = emb[(size_t)(nbase + n) * 256 + kbase + k];
            }
            __syncthreads();
#pragma unroll 8
            for (int k = 0; k < 64; ++k) {
                float4 a  = *(const float4*)&As[k][tx * 4];
                float4 bv = *(const float4*)&Bs[k][ty * 4];
                acc[0][0] += a.x * bv.x; acc[0][1] += a.x * bv.y;
                acc[0][2] += a.x * bv.z; acc[0][3] += a.x * bv.w;
                acc[1][0] += a.y * bv.x; acc[1][1] += a.y * bv.y;
                acc[1][2] += a.y * bv.z; acc[1][3] += a.y * bv.w;
                acc[2][0] += a.z * bv.x; acc[2][1] += a.z * bv.y;
                acc[2][2] += a.z * bv.z; acc[2][3] += a.z * bv.w;
                acc[3][0] += a.w * bv.x; acc[3][1] += a.w * bv.y;
                acc[3][2] += a.w * bv.z; acc[3][3] += a.w * bv.w;
            }
            __syncthreads();
        }
        // d = fl32(fl32(S+E) - 2*M), argmin with lowest-index tie-break.
#pragma unroll
        for (int j = 0; j < 4; ++j) {
            int col = nbase + ty * 4 + j;
            float Ej = E[col];
#pragma unroll
            for (int i = 0; i < 4; ++i) {
                float t = Sr[i] + Ej;
                float d = t - 2.0f * acc[i][j];
                if (d < bd[i] || (d == bd[i] && col < bj[i])) { bd[i] = d; bj[i] = col; }
            }
        }
    }

    // reduce across the 16 col-groups sharing each row (lexicographic).
    float* sd = &As[0][0];
    int*   sj = (int*)&Bs[0][0];
#pragma unroll
    for (int i = 0; i < 4; ++i) {
        sd[ty * 64 + tx * 4 + i] = bd[i];
        sj[ty * 64 + tx * 4 + i] = bj[i];
    }
    __syncthreads();
    if (tid < 64) {
        float best = __builtin_inff(); int bestj = 0x7fffffff;
        for (int t = 0; t < 16; ++t) {
            float d = sd[t * 64 + tid];
            int   j = sj[t * 64 + tid];
            if (d < best || (d == best && j < bestj)) { best = d; bestj = j; }
        }
        bd_out[(size_t)(row0 + tid) * NSPLIT + blockIdx.y] = best;
        bj_out[(size_t)(row0 + tid) * NSPLIT + blockIdx.y] = bestj;
    }
}

// merge NSPLIT candidates per row; splits cover ascending j ranges.
__global__ void k_merge(const float* __restrict__ bd, const int* __restrict__ bj,
                        int* __restrict__ idx, float* __restrict__ idx_f) {
    int r = blockIdx.x * 256 + threadIdx.x;
    float best = __builtin_inff(); int bestj = 0x7fffffff;
#pragma unroll
    for (int s = 0; s < NSPLIT; ++s) {
        float d = bd[(size_t)r * NSPLIT + s];
        int   j = bj[(size_t)r * NSPLIT + s];
        if (d < best || (d == best && j < bestj)) { best = d; bestj = j; }
    }
    idx[r] = bestj;
    idx_f[r] = (float)bestj;   // indices output (float32 buffer)
}

// out[b][c][h][w] = fl(zp + fl(zq - zp)); loss partial = fl(zq-zp)^2.
__global__ void k_out(const float* __restrict__ z, const float* __restrict__ emb,
                      const int* __restrict__ idx, float* __restrict__ out,
                      float* __restrict__ loss_acc) {
    int flat = blockIdx.x * 256 + threadIdx.x;
    int b = flat >> 18;
    int c = (flat >> 10) & 255;
    int hw = flat & 1023;
    int r = (b << 10) | hw;
    float zp = z[flat];
    float zq = emb[(size_t)idx[r] * 256 + c];
    float diff = zq - zp;
    out[flat] = zp + diff;
    float v = diff * diff;
    __shared__ float red[256];
    red[threadIdx.x] = v;
    __syncthreads();
    for (int off = 128; off; off >>= 1) {
        if (threadIdx.x < off) red[threadIdx.x] += red[threadIdx.x + off];
        __syncthreads();
    }
    if (threadIdx.x == 0) atomicAdd(loss_acc, red[0]);
}

__global__ void k_fin(const float* __restrict__ loss_acc, float* __restrict__ out_loss) {
    float m = loss_acc[0] / 4194304.0f;
    out_loss[0] = m + 0.25f * m;
}

extern "C" void kernel_launch(void* const* d_in, const int* in_sizes, int n_in,
                              void* d_out, int out_size, void* d_ws, size_t ws_size,
                              hipStream_t stream) {
    const float* z   = (const float*)d_in[0];
    const float* emb = (const float*)d_in[1];
    float* out = (float*)d_out;
    float* ws  = (float*)d_ws;

    float* S    = ws + WS_S;
    float* E    = ws + WS_E;
    float* BD   = ws + WS_BD;
    int*   BJ   = (int*)(ws + WS_BJ);
    int*   IDX  = (int*)(ws + WS_IDX);
    float* LOSS = ws + WS_LOSS;

    k_rowsum_z<<<NROWS / 256, 256, 0, stream>>>(z, S);
    k_rowsum_e<<<NE / 4, 256, 0, stream>>>(emb, E);

    dim3 g(NROWS / 64, NSPLIT);
    k_gemm_argmin<<<g, 256, 0, stream>>>(z, emb, S, E, BD, BJ);

    k_merge<<<NROWS / 256, 256, 0, stream>>>(BD, BJ, IDX, out + OUT_N + 1);

    hipMemsetAsync(LOSS, 0, sizeof(float), stream);
    k_out<<<OUT_N / 256, 256, 0, stream>>>(z, emb, IDX, out, LOSS);
    k_fin<<<1, 1, 0, stream>>>(LOSS, out + OUT_N);
}

// Round 2
// 1031.434 us; speedup vs baseline: 1.3126x; 1.3126x over previous
//
#include <hip/hip_runtime.h>

#define NROWS 16384      // 16*32*32
#define EDIM  256
#define NE    8192
#define OUT_N 4194304    // 16*256*32*32

// ws layout, offsets in 4-byte units
#define WS_S    0
#define WS_E    (WS_S + NROWS)            // 16384
#define WS_KEY  (WS_E + NE)               // 24576 (even -> 8B aligned)
#define WS_IDX  (WS_KEY + NROWS * 2)      // keys are u64 = 2 floats each
#define WS_LOSS (WS_IDX + NROWS)

// ---------------- row sums ----------------
__global__ void k_rowsum_z(const float* __restrict__ z, float* __restrict__ S) {
    int r = blockIdx.x * 256 + threadIdx.x;
    int b = r >> 10, hw = r & 1023;
    const float* p = z + (size_t)b * 262144 + hw;
    double s = 0.0;
#pragma unroll 8
    for (int c = 0; c < 256; ++c) {
        float v = p[(size_t)c * 1024];
        s += (double)v * (double)v;
    }
    S[r] = (float)s;
}

__global__ void k_rowsum_e(const float* __restrict__ emb, float* __restrict__ E) {
    int row  = blockIdx.x * 4 + (threadIdx.x >> 6);
    int lane = threadIdx.x & 63;
    const float* p = emb + (size_t)row * 256;
    double s = 0.0;
#pragma unroll
    for (int i = 0; i < 4; ++i) {
        float v = p[lane + i * 64];
        s += (double)v * (double)v;
    }
    for (int off = 32; off; off >>= 1) s += __shfl_down(s, off, 64);
    if (lane == 0) E[row] = (float)s;
}

// ---------------- 128x128x(BK=32) GEMM + argmin ----------------
// grid (NROWS/128, NE/128), block 256 = 16x16 micro-tiles of 8x8 (split 4+4).
__global__ __launch_bounds__(256, 4) void k_gemm_argmin(
    const float* __restrict__ z, const float* __restrict__ emb,
    const float* __restrict__ S, const float* __restrict__ E,
    unsigned long long* __restrict__ keys) {
    __shared__ __align__(16) float As[32][128];   // [k][m] 16 KB
    __shared__ __align__(16) float Bs[32][132];   // [k][n] +4 pad: conflict-free writes

    const int tid = threadIdx.x;
    const int tx = tid & 15;       // row group
    const int ty = tid >> 4;       // col group
    const int row0 = blockIdx.x * 128;
    const int col0 = blockIdx.y * 128;
    const int b = row0 >> 10, hw0 = row0 & 1023;  // 128-row tile never crosses b
    const float* zb = z + (size_t)b * 262144 + hw0;

    float acc[8][8];
#pragma unroll
    for (int i = 0; i < 8; ++i)
#pragma unroll
        for (int j = 0; j < 8; ++j) acc[i][j] = 0.0f;

    for (int kt = 0; kt < 8; ++kt) {
        const int kbase = kt * 32;
        // A: 32 k x 128 m, float4 along m (coalesced; conflict-free LDS writes)
#pragma unroll
        for (int it = 0; it < 4; ++it) {
            int e = tid + it * 256;            // 0..1023 float4 slots
            int k = e >> 5, m4 = (e & 31) << 2;
            *(float4*)&As[k][m4] = *(const float4*)(zb + (size_t)(kbase + k) * 1024 + m4);
        }
        // B: 128 n x 32 k, float4 along k (coalesced); scalar LDS writes,
        // bank = (16*kl + 4*i + n) % 32 -> conflict-free with the 132 pad.
#pragma unroll
        for (int it = 0; it < 4; ++it) {
            int e = tid + it * 256;            // 0..1023 float4 slots
            int n = e >> 3, k4 = (e & 7) << 2;
            float4 v = *(const float4*)(emb + (size_t)(col0 + n) * 256 + kbase + k4);
            Bs[k4 + 0][n] = v.x; Bs[k4 + 1][n] = v.y;
            Bs[k4 + 2][n] = v.z; Bs[k4 + 3][n] = v.w;
        }
        __syncthreads();
#pragma unroll 8
        for (int k = 0; k < 32; ++k) {
            float4 a0 = *(const float4*)&As[k][tx * 4];
            float4 a1 = *(const float4*)&As[k][64 + tx * 4];
            float4 b0 = *(const float4*)&Bs[k][ty * 4];
            float4 b1 = *(const float4*)&Bs[k][64 + ty * 4];
            float a_[8] = {a0.x, a0.y, a0.z, a0.w, a1.x, a1.y, a1.z, a1.w};
            float b_[8] = {b0.x, b0.y, b0.z, b0.w, b1.x, b1.y, b1.z, b1.w};
#pragma unroll
            for (int i = 0; i < 8; ++i)
#pragma unroll
                for (int j = 0; j < 8; ++j) acc[i][j] += a_[i] * b_[j];
        }
        __syncthreads();
    }

    // epilogue: d = fl(fl(S+E) - 2*acc); pack (d, col) -> u64, min = lexicographic.
    float4 S0 = *(const float4*)(S + row0 + tx * 4);
    float4 S1 = *(const float4*)(S + row0 + 64 + tx * 4);
    float4 E0 = *(const float4*)(E + col0 + ty * 4);
    float4 E1 = *(const float4*)(E + col0 + 64 + ty * 4);
    float Sr[8] = {S0.x, S0.y, S0.z, S0.w, S1.x, S1.y, S1.z, S1.w};
    float Ec[8] = {E0.x, E0.y, E0.z, E0.w, E1.x, E1.y, E1.z, E1.w};

    unsigned long long best[8];
#pragma unroll
    for (int i = 0; i < 8; ++i) best[i] = ~0ull;
#pragma unroll
    for (int j = 0; j < 8; ++j) {
        int col = col0 + ((j < 4) ? (ty * 4 + j) : (64 + ty * 4 + j - 4));
#pragma unroll
        for (int i = 0; i < 8; ++i) {
            float t = Sr[i] + Ec[j];
            float d = t - 2.0f * acc[i][j];
            unsigned ud = __float_as_uint(d);
            ud = (ud & 0x80000000u) ? ~ud : (ud | 0x80000000u);
            unsigned long long key = ((unsigned long long)ud << 32) | (unsigned)col;
            if (key < best[i]) best[i] = key;
        }
    }

    __syncthreads();   // done reading As/Bs; reuse As as u64 scratch
    unsigned long long* Sk = (unsigned long long*)&As[0][0];   // 16 x 128 u64 = 16 KB
#pragma unroll
    for (int i = 0; i < 4; ++i) {
        Sk[ty * 128 + tx * 4 + i]      = best[i];
        Sk[ty * 128 + 64 + tx * 4 + i] = best[4 + i];
    }
    __syncthreads();
    if (tid < 128) {
        unsigned long long m = ~0ull;
#pragma unroll
        for (int t = 0; t < 16; ++t) {
            unsigned long long v = Sk[t * 128 + tid];
            m = v < m ? v : m;
        }
        atomicMin(&keys[row0 + tid], m);
    }
}

// unpack keys -> idx (int) and idx_f (float output)
__global__ void k_merge(const unsigned long long* __restrict__ keys,
                        int* __restrict__ idx, float* __restrict__ idx_f) {
    int r = blockIdx.x * 256 + threadIdx.x;
    int bestj = (int)(keys[r] & 0xFFFFFFFFull);
    idx[r] = bestj;
    idx_f[r] = (float)bestj;
}

// out[b][c][h][w] = fl(zp + fl(zq - zp)); loss partial = fl(zq-zp)^2.
__global__ void k_out(const float* __restrict__ z, const float* __restrict__ emb,
                      const int* __restrict__ idx, float* __restrict__ out,
                      float* __restrict__ loss_acc) {
    int flat = blockIdx.x * 256 + threadIdx.x;
    int b = flat >> 18;
    int c = (flat >> 10) & 255;
    int hw = flat & 1023;
    int r = (b << 10) | hw;
    float zp = z[flat];
    float zq = emb[(size_t)idx[r] * 256 + c];
    float diff = zq - zp;
    out[flat] = zp + diff;
    float v = diff * diff;
    __shared__ float red[256];
    red[threadIdx.x] = v;
    __syncthreads();
    for (int off = 128; off; off >>= 1) {
        if (threadIdx.x < off) red[threadIdx.x] += red[threadIdx.x + off];
        __syncthreads();
    }
    if (threadIdx.x == 0) atomicAdd(loss_acc, red[0]);
}

__global__ void k_fin(const float* __restrict__ loss_acc, float* __restrict__ out_loss) {
    float m = loss_acc[0] / 4194304.0f;
    out_loss[0] = m + 0.25f * m;
}

extern "C" void kernel_launch(void* const* d_in, const int* in_sizes, int n_in,
                              void* d_out, int out_size, void* d_ws, size_t ws_size,
                              hipStream_t stream) {
    const float* z   = (const float*)d_in[0];
    const float* emb = (const float*)d_in[1];
    float* out = (float*)d_out;
    float* ws  = (float*)d_ws;

    float* S    = ws + WS_S;
    float* E    = ws + WS_E;
    unsigned long long* KEYS = (unsigned long long*)(ws + WS_KEY);
    int*   IDX  = (int*)(ws + WS_IDX);
    float* LOSS = ws + WS_LOSS;

    k_rowsum_z<<<NROWS / 256, 256, 0, stream>>>(z, S);
    k_rowsum_e<<<NE / 4, 256, 0, stream>>>(emb, E);

    hipMemsetAsync(KEYS, 0xFF, NROWS * sizeof(unsigned long long), stream);
    dim3 g(NROWS / 128, NE / 128);
    k_gemm_argmin<<<g, 256, 0, stream>>>(z, emb, S, E, KEYS);

    k_merge<<<NROWS / 256, 256, 0, stream>>>(KEYS, IDX, out + OUT_N + 1);

    hipMemsetAsync(LOSS, 0, sizeof(float), stream);
    k_out<<<OUT_N / 256, 256, 0, stream>>>(z, emb, IDX, out, LOSS);
    k_fin<<<1, 1, 0, stream>>>(LOSS, out + OUT_N);
}